// Round 4
// baseline (486.697 us; speedup 1.0000x reference)
//
#include <hip/hip_runtime.h>
#include <hip/hip_cooperative_groups.h>
#include <math.h>

namespace cg = cooperative_groups;

// x shape (64, 256, 56, 56) fp32. Per-sample min/max -> fake quant -> dequant -> ReLU6.
// Sample = 802816 floats = 200704 float4. 64 samples x 16 blocks = 1024 blocks
// (4 blocks/CU at 256 thr -> all co-resident; cooperative launch).

#define SAMPLE_V4    200704
#define NSAMPLES     64
#define BPS          16              // blocks per sample
#define V4_PER_BLK   12544           // 200704 / 16

typedef __attribute__((ext_vector_type(4))) float fvec4;

__device__ __forceinline__ float qr_apply1(float x, float m, float sc, float inv) {
    float k = rintf((x - m) * inv - 127.0f);       // half-to-even == jnp.round
    float y = fmaf(k + 127.0f, sc, m);
    return fminf(fmaxf(y, 0.0f), 6.0f);
}

__global__ __launch_bounds__(256) void qr_fused(const float4* __restrict__ x,
                                                float4* __restrict__ y,
                                                float* __restrict__ pmin,
                                                float* __restrict__ pmax) {
    const int s = blockIdx.x >> 4;          // sample
    const int b = blockIdx.x & (BPS - 1);   // chunk within sample
    const size_t off = (size_t)s * SAMPLE_V4 + (size_t)b * V4_PER_BLK;
    const float4* xb = x + off;

    // ---- phase 1: per-block partial min/max (49 coalesced float4 iters) ----
    float mn = INFINITY, mx = -INFINITY;
    for (int i = threadIdx.x; i < V4_PER_BLK; i += 256) {
        float4 v = xb[i];
        mn = fminf(mn, fminf(fminf(v.x, v.y), fminf(v.z, v.w)));
        mx = fmaxf(mx, fmaxf(fmaxf(v.x, v.y), fmaxf(v.z, v.w)));
    }
    #pragma unroll
    for (int o = 32; o > 0; o >>= 1) {
        mn = fminf(mn, __shfl_down(mn, o, 64));
        mx = fmaxf(mx, __shfl_down(mx, o, 64));
    }
    __shared__ float smn[4], smx[4];
    const int wave = threadIdx.x >> 6;
    if ((threadIdx.x & 63) == 0) { smn[wave] = mn; smx[wave] = mx; }
    __syncthreads();
    if (threadIdx.x == 0) {
        pmin[blockIdx.x] = fminf(fminf(smn[0], smn[1]), fminf(smn[2], smn[3]));
        pmax[blockIdx.x] = fmaxf(fmaxf(smx[0], smx[1]), fmaxf(smx[2], smx[3]));
    }

    cg::this_grid().sync();

    // ---- finalize: reduce this sample's 16 partials (L2-hit reads) ----
    __shared__ float sp[3];
    if (threadIdx.x < 64) {
        float fmn = (threadIdx.x < BPS) ? pmin[s * BPS + threadIdx.x] : INFINITY;
        float fmx = (threadIdx.x < BPS) ? pmax[s * BPS + threadIdx.x] : -INFINITY;
        #pragma unroll
        for (int o = 8; o > 0; o >>= 1) {
            fmn = fminf(fmn, __shfl_down(fmn, o, 64));
            fmx = fmaxf(fmx, __shfl_down(fmx, o, 64));
        }
        if (threadIdx.x == 0) {
            const float rng = fmx - fmn;
            sp[0] = fmn;
            sp[1] = rng * (1.0f / 254.0f);
            sp[2] = 254.0f / rng;
        }
    }
    __syncthreads();
    const float m = sp[0], sc = sp[1], inv = sp[2];

    // ---- phase 2: apply; re-read own chunk (L3-resident), nt streaming store ----
    fvec4* yb = (fvec4*)(y + off);
    for (int i = threadIdx.x; i < V4_PER_BLK; i += 256) {
        float4 v = xb[i];
        fvec4 o;
        o.x = qr_apply1(v.x, m, sc, inv);
        o.y = qr_apply1(v.y, m, sc, inv);
        o.z = qr_apply1(v.z, m, sc, inv);
        o.w = qr_apply1(v.w, m, sc, inv);
        __builtin_nontemporal_store(o, &yb[i]);
    }
}

extern "C" void kernel_launch(void* const* d_in, const int* in_sizes, int n_in,
                              void* d_out, int out_size, void* d_ws, size_t ws_size,
                              hipStream_t stream) {
    const float4* x = (const float4*)d_in[0];
    float4* out = (float4*)d_out;
    float* pmin = (float*)d_ws;                 // 64*16 floats
    float* pmax = pmin + NSAMPLES * BPS;

    void* args[] = {(void*)&x, (void*)&out, (void*)&pmin, (void*)&pmax};
    hipLaunchCooperativeKernel((void*)qr_fused, dim3(NSAMPLES * BPS), dim3(256),
                               args, 0, stream);
}

// Round 5
// 370.201 us; speedup vs baseline: 1.3147x; 1.3147x over previous
//
#include <hip/hip_runtime.h>
#include <math.h>

// x shape (64, 256, 56, 56) fp32. Per-sample min/max -> fake quant -> dequant -> ReLU6.
// Sample = 802816 floats = 200704 float4.
// Two kernels, oversubscribed grids (R4 lesson: 4 blocks/CU coop grid ran at
// 1.7 TB/s; scheduler-pipelined 12-24 blocks/CU grids hide HBM latency).

#define SAMPLE_V4    200704
#define NSAMPLES     64
#define BPS_R        49              // reduce blocks per sample -> 3136 blocks
#define V4_PER_BLK_R 4096            // 200704 / 49
#define BPS_E        98              // apply blocks per sample -> 6272 blocks
#define V4_PER_BLK_E 2048            // 200704 / 98

typedef __attribute__((ext_vector_type(4))) float fvec4;

__global__ __launch_bounds__(256) void qr_reduce(const float4* __restrict__ x,
                                                 float* __restrict__ pmin,
                                                 float* __restrict__ pmax) {
    const int s = blockIdx.x / BPS_R;
    const int b = blockIdx.x % BPS_R;
    const float4* base = x + (size_t)s * SAMPLE_V4 + (size_t)b * V4_PER_BLK_R;

    // 16 iters of float4; 2 independent accumulator pairs -> 2+ loads in flight.
    float mn0 = INFINITY, mx0 = -INFINITY, mn1 = INFINITY, mx1 = -INFINITY;
    for (int i = threadIdx.x; i < V4_PER_BLK_R; i += 512) {
        float4 v0 = base[i];
        float4 v1 = base[i + 256];
        mn0 = fminf(mn0, fminf(fminf(v0.x, v0.y), fminf(v0.z, v0.w)));
        mx0 = fmaxf(mx0, fmaxf(fmaxf(v0.x, v0.y), fmaxf(v0.z, v0.w)));
        mn1 = fminf(mn1, fminf(fminf(v1.x, v1.y), fminf(v1.z, v1.w)));
        mx1 = fmaxf(mx1, fmaxf(fmaxf(v1.x, v1.y), fmaxf(v1.z, v1.w)));
    }
    float mn = fminf(mn0, mn1), mx = fmaxf(mx0, mx1);
    #pragma unroll
    for (int o = 32; o > 0; o >>= 1) {
        mn = fminf(mn, __shfl_down(mn, o, 64));
        mx = fmaxf(mx, __shfl_down(mx, o, 64));
    }
    __shared__ float smn[4], smx[4];
    const int wave = threadIdx.x >> 6;
    if ((threadIdx.x & 63) == 0) { smn[wave] = mn; smx[wave] = mx; }
    __syncthreads();
    if (threadIdx.x == 0) {
        pmin[blockIdx.x] = fminf(fminf(smn[0], smn[1]), fminf(smn[2], smn[3]));
        pmax[blockIdx.x] = fmaxf(fmaxf(smx[0], smx[1]), fmaxf(smx[2], smx[3]));
    }
}

__device__ __forceinline__ float qr_apply1(float x, float m, float sc, float inv) {
    float k = rintf((x - m) * inv - 127.0f);       // half-to-even == jnp.round
    float y = fmaf(k + 127.0f, sc, m);
    return fminf(fmaxf(y, 0.0f), 6.0f);
}

__global__ __launch_bounds__(256) void qr_apply(const float4* __restrict__ x,
                                                float4* __restrict__ y,
                                                const float* __restrict__ pmin,
                                                const float* __restrict__ pmax) {
    const int s = blockIdx.x / BPS_E;
    const int b = blockIdx.x % BPS_E;

    // Per-block finalize of this sample's 49 partials (L2-hit reads, ~0.2 KB).
    __shared__ float sp[3];
    if (threadIdx.x < 64) {
        float fmn = (threadIdx.x < BPS_R) ? pmin[s * BPS_R + threadIdx.x] : INFINITY;
        float fmx = (threadIdx.x < BPS_R) ? pmax[s * BPS_R + threadIdx.x] : -INFINITY;
        #pragma unroll
        for (int o = 32; o > 0; o >>= 1) {
            fmn = fminf(fmn, __shfl_down(fmn, o, 64));
            fmx = fmaxf(fmx, __shfl_down(fmx, o, 64));
        }
        if (threadIdx.x == 0) {
            const float rng = fmx - fmn;
            sp[0] = fmn;
            sp[1] = rng * (1.0f / 254.0f);
            sp[2] = 254.0f / rng;
        }
    }
    __syncthreads();
    const float m = sp[0], sc = sp[1], inv = sp[2];

    const size_t off = (size_t)s * SAMPLE_V4 + (size_t)b * V4_PER_BLK_E;
    const float4* xb = x + off;
    fvec4* yb = (fvec4*)(y + off);
    // 8 iters; reads hit L3 (x just streamed by qr_reduce), nt streaming stores.
    for (int i = threadIdx.x; i < V4_PER_BLK_E; i += 256) {
        float4 v = xb[i];
        fvec4 o;
        o.x = qr_apply1(v.x, m, sc, inv);
        o.y = qr_apply1(v.y, m, sc, inv);
        o.z = qr_apply1(v.z, m, sc, inv);
        o.w = qr_apply1(v.w, m, sc, inv);
        __builtin_nontemporal_store(o, &yb[i]);
    }
}

extern "C" void kernel_launch(void* const* d_in, const int* in_sizes, int n_in,
                              void* d_out, int out_size, void* d_ws, size_t ws_size,
                              hipStream_t stream) {
    const float* x = (const float*)d_in[0];
    float* out = (float*)d_out;

    float* pmin = (float*)d_ws;                 // 64*49 floats
    float* pmax = pmin + NSAMPLES * BPS_R;      // 64*49 floats

    qr_reduce<<<NSAMPLES * BPS_R, 256, 0, stream>>>((const float4*)x, pmin, pmax);
    qr_apply<<<NSAMPLES * BPS_E, 256, 0, stream>>>((const float4*)x, (float4*)out,
                                                   pmin, pmax);
}

// Round 6
// 367.309 us; speedup vs baseline: 1.3250x; 1.0079x over previous
//
#include <hip/hip_runtime.h>
#include <math.h>

// x shape (64, 256, 56, 56) fp32. Per-sample min/max -> fake quant -> dequant -> ReLU6.
// Sample = 802816 floats = 200704 float4.
// Two kernels. R4 lesson: no grid.sync (1.7 TB/s disaster). R5 lesson: TLP already
// sufficient; this round cuts per-block preamble count (apply 98->49 blocks/sample)
// and deepens MLP (4 load streams in reduce, 2 in apply).

#define SAMPLE_V4    200704
#define NSAMPLES     64
#define BPS          49              // blocks per sample, both kernels -> 3136 blocks
#define V4_PER_BLK   4096            // 200704 / 49 (64 KB per block)

typedef __attribute__((ext_vector_type(4))) float fvec4;

__device__ __forceinline__ void acc_minmax(float4 v, float& mn, float& mx) {
    mn = fminf(mn, fminf(fminf(v.x, v.y), fminf(v.z, v.w)));
    mx = fmaxf(mx, fmaxf(fmaxf(v.x, v.y), fmaxf(v.z, v.w)));
}

__global__ __launch_bounds__(256) void qr_reduce(const float4* __restrict__ x,
                                                 float* __restrict__ pmin,
                                                 float* __restrict__ pmax) {
    const int s = blockIdx.x / BPS;
    const int b = blockIdx.x % BPS;
    const float4* base = x + (size_t)s * SAMPLE_V4 + (size_t)b * V4_PER_BLK;

    // 4096 float4 / 256 thr = 16 loads/thr; 4 independent streams -> 4 in flight.
    float mn0 = INFINITY, mx0 = -INFINITY, mn1 = INFINITY, mx1 = -INFINITY;
    float mn2 = INFINITY, mx2 = -INFINITY, mn3 = INFINITY, mx3 = -INFINITY;
    for (int i = threadIdx.x; i < V4_PER_BLK; i += 1024) {
        float4 v0 = base[i];
        float4 v1 = base[i + 256];
        float4 v2 = base[i + 512];
        float4 v3 = base[i + 768];
        acc_minmax(v0, mn0, mx0);
        acc_minmax(v1, mn1, mx1);
        acc_minmax(v2, mn2, mx2);
        acc_minmax(v3, mn3, mx3);
    }
    float mn = fminf(fminf(mn0, mn1), fminf(mn2, mn3));
    float mx = fmaxf(fmaxf(mx0, mx1), fmaxf(mx2, mx3));
    #pragma unroll
    for (int o = 32; o > 0; o >>= 1) {
        mn = fminf(mn, __shfl_down(mn, o, 64));
        mx = fmaxf(mx, __shfl_down(mx, o, 64));
    }
    __shared__ float smn[4], smx[4];
    const int wave = threadIdx.x >> 6;
    if ((threadIdx.x & 63) == 0) { smn[wave] = mn; smx[wave] = mx; }
    __syncthreads();
    if (threadIdx.x == 0) {
        pmin[blockIdx.x] = fminf(fminf(smn[0], smn[1]), fminf(smn[2], smn[3]));
        pmax[blockIdx.x] = fmaxf(fmaxf(smx[0], smx[1]), fmaxf(smx[2], smx[3]));
    }
}

__device__ __forceinline__ float qr_apply1(float x, float m, float sc, float inv) {
    float k = rintf((x - m) * inv - 127.0f);       // half-to-even == jnp.round
    float y = fmaf(k + 127.0f, sc, m);
    return fminf(fmaxf(y, 0.0f), 6.0f);
}

__device__ __forceinline__ fvec4 qr_apply4(float4 v, float m, float sc, float inv) {
    fvec4 o;
    o.x = qr_apply1(v.x, m, sc, inv);
    o.y = qr_apply1(v.y, m, sc, inv);
    o.z = qr_apply1(v.z, m, sc, inv);
    o.w = qr_apply1(v.w, m, sc, inv);
    return o;
}

__global__ __launch_bounds__(256) void qr_apply(const float4* __restrict__ x,
                                                float4* __restrict__ y,
                                                const float* __restrict__ pmin,
                                                const float* __restrict__ pmax) {
    const int s = blockIdx.x / BPS;
    const int b = blockIdx.x % BPS;

    // Per-block finalize of this sample's 49 partials (L2-hit, ~0.4 KB).
    __shared__ float sp[3];
    if (threadIdx.x < 64) {
        float fmn = (threadIdx.x < BPS) ? pmin[s * BPS + threadIdx.x] : INFINITY;
        float fmx = (threadIdx.x < BPS) ? pmax[s * BPS + threadIdx.x] : -INFINITY;
        #pragma unroll
        for (int o = 32; o > 0; o >>= 1) {
            fmn = fminf(fmn, __shfl_down(fmn, o, 64));
            fmx = fmaxf(fmx, __shfl_down(fmx, o, 64));
        }
        if (threadIdx.x == 0) {
            const float rng = fmx - fmn;
            sp[0] = fmn;
            sp[1] = rng * (1.0f / 254.0f);
            sp[2] = 254.0f / rng;
        }
    }
    __syncthreads();
    const float m = sp[0], sc = sp[1], inv = sp[2];

    const size_t off = (size_t)s * SAMPLE_V4 + (size_t)b * V4_PER_BLK;
    const float4* xb = x + off;
    fvec4* yb = (fvec4*)(y + off);
    // 16 loads/thr, 2 streams; reads L3-hit (x just streamed by qr_reduce),
    // nt stores keep x resident / avoid write-allocate pollution.
    for (int i = threadIdx.x; i < V4_PER_BLK; i += 512) {
        float4 v0 = xb[i];
        float4 v1 = xb[i + 256];
        fvec4 o0 = qr_apply4(v0, m, sc, inv);
        fvec4 o1 = qr_apply4(v1, m, sc, inv);
        __builtin_nontemporal_store(o0, &yb[i]);
        __builtin_nontemporal_store(o1, &yb[i + 256]);
    }
}

extern "C" void kernel_launch(void* const* d_in, const int* in_sizes, int n_in,
                              void* d_out, int out_size, void* d_ws, size_t ws_size,
                              hipStream_t stream) {
    const float* x = (const float*)d_in[0];
    float* out = (float*)d_out;

    float* pmin = (float*)d_ws;                 // 64*49 floats
    float* pmax = pmin + NSAMPLES * BPS;        // 64*49 floats

    qr_reduce<<<NSAMPLES * BPS, 256, 0, stream>>>((const float4*)x, pmin, pmax);
    qr_apply<<<NSAMPLES * BPS, 256, 0, stream>>>((const float4*)x, (float4*)out,
                                                 pmin, pmax);
}